// Round 5
// baseline (192.231 us; speedup 1.0000x reference)
//
#include <hip/hip_runtime.h>
#include <hip/hip_bf16.h>
#include <stdint.h>

#define NTOK 4096
#define DIM  256
#define NH   8
#define HD   32
#define MAXNNZ 512   // per-row neighbor list capacity (mean ~205)

typedef __attribute__((ext_vector_type(8))) short short8;
typedef __attribute__((ext_vector_type(4))) float float4v;
typedef __attribute__((ext_vector_type(2))) float f32x2;
typedef __attribute__((ext_vector_type(2))) _Float16 h2;
typedef unsigned short u16;
typedef unsigned int u32;

__device__ __forceinline__ float bf2f(u16 u) {
    union { u32 u; float f; } c; c.u = ((u32)u) << 16; return c.f;
}
__device__ __forceinline__ u16 f2bf(float f) {        // RNE
    union { float f; u32 u; } c; c.f = f;
    u32 u = c.u;
    u = u + 0x7FFFu + ((u >> 16) & 1u);
    return (u16)(u >> 16);
}
__device__ __forceinline__ u16 f2h(float f) {         // f32 -> f16 bits
    union { _Float16 h; u16 u; } c; c.h = (_Float16)f; return c.u;
}
__device__ __forceinline__ h2 bch2(u32 v) {           // u32 -> half2
    union { u32 u; h2 h; } c; c.u = v; return c.h;
}
// unpack a packed bf16 pair (u32) to two f32 without shifts on the hi half
__device__ __forceinline__ float blo(u32 c) {
    union { u32 u; float f; } x; x.u = c << 16; return x.f;
}
__device__ __forceinline__ float bhi(u32 c) {
    union { u32 u; float f; } x; x.u = c & 0xFFFF0000u; return x.f;
}
// sum across the 4-lane quad (lane bits 0-1) via DPP quad_perm — pure VALU,
// replaces 2 ds_swizzle round-trips (LDS pipe, ~30cy each, serial in the
// per-neighbor chain).
__device__ __forceinline__ float qsum4(float s) {
    union { float f; int i; } c, r;
    c.f = s;
    r.i = __builtin_amdgcn_mov_dpp(c.i, 0xB1, 0xF, 0xF, true);  // [1,0,3,2]
    c.f += r.f;
    r.i = __builtin_amdgcn_mov_dpp(c.i, 0x4E, 0xF, 0xF, true);  // [2,3,0,1]
    return c.f + r.f;
}

// ---------------- kernel A: x (f32) -> bf16 ----------------
__global__ void x_to_bf16(const float* __restrict__ x, u16* __restrict__ xb) {
    int i = (blockIdx.x * blockDim.x + threadIdx.x) * 4;
    float4 v = *(const float4*)(x + i);
    ushort4 o;
    o.x = f2bf(v.x); o.y = f2bf(v.y); o.z = f2bf(v.z); o.w = f2bf(v.w);
    *(ushort4*)(xb + i) = o;
}

// ---------------- kernel 0: transpose weights (f32 256x256 -> bf16 WT) ----------------
__global__ void transpose_w(const float* __restrict__ Wq, const float* __restrict__ Wk,
                            const float* __restrict__ Wv, const float* __restrict__ Wo,
                            u16* __restrict__ WT) {
    const float* srcs[4] = {Wq, Wk, Wv, Wo};
    const float* W = srcs[blockIdx.y];
    int o = blockIdx.x, i = threadIdx.x;
    WT[blockIdx.y * 65536 + o * 256 + i] = f2bf(W[i * 256 + o]);
}

// ---------------- kernel 1: adj (f32) -> per-row neighbor lists ----------------
__global__ __launch_bounds__(256) void adj_to_list(const float* __restrict__ adj,
                                                   u16* __restrict__ NL,
                                                   u32* __restrict__ NC) {
    __shared__ u32 cnt;
    int row = blockIdx.x, t = threadIdx.x;
    if (t == 0) cnt = 0;
    __syncthreads();
    const float4* rp = (const float4*)(adj + (size_t)row * NTOK);
    u16* lbase = NL + (size_t)row * MAXNNZ;
#pragma unroll
    for (int i = 0; i < 4; ++i) {
        float4 v = rp[i * 256 + t];
        u32 m = 0;
        if (v.x != 0.f) m |= 1u;
        if (v.y != 0.f) m |= 2u;
        if (v.z != 0.f) m |= 4u;
        if (v.w != 0.f) m |= 8u;
        if (m) {
            int p = __popc(m);
            u32 base = atomicAdd(&cnt, (u32)p);
            int col0 = (i * 256 + t) * 4;
            while (m) {
                int j = __builtin_ctz(m);
                m &= m - 1;
                if (base < MAXNNZ) lbase[base] = (u16)(col0 + j);
                ++base;
            }
        }
    }
    __syncthreads();
    if (t == 0) NC[row] = (cnt < MAXNNZ) ? cnt : MAXNNZ;
}

// ---------------- kernel 2: QKV projection -----------------------------------
// Q, K written as f16 (feeds v_dot2_f32_f16 in sparse_attn); V stays bf16.
__global__ __launch_bounds__(64) void qkv_gemm(
    const u16* __restrict__ xb,
    const u16* __restrict__ WT,
    const float* __restrict__ bq, const float* __restrict__ bk, const float* __restrict__ bv,
    u16* __restrict__ Q, u16* __restrict__ K, u16* __restrict__ V) {
    int lane = threadIdx.x, quad = lane >> 4, l16 = lane & 15;
    int mtile = blockIdx.x, ntile = blockIdx.y, mat = blockIdx.z;
    const float* bias = (mat == 0) ? bq : (mat == 1) ? bk : bv;
    const u16* arow = xb + (size_t)(mtile * 16 + l16) * DIM + quad * 8;
    const u16* brow = WT + (size_t)mat * 65536 + (size_t)(ntile * 16 + l16) * DIM + quad * 8;
    float4v acc = {0.f, 0.f, 0.f, 0.f};
#pragma unroll
    for (int k0 = 0; k0 < DIM; k0 += 32) {
        short8 af = *(const short8*)(arow + k0);
        short8 bf = *(const short8*)(brow + k0);
        acc = __builtin_amdgcn_mfma_f32_16x16x32_bf16(af, bf, acc, 0, 0, 0);
    }
    int n = ntile * 16 + l16;
    float bb = bias[n];
    const float sc = (mat == 0) ? 0.25503635559913516f : 1.0f;  // 1/sqrt(32)*log2e
    u16* dst = (mat == 0) ? Q : (mat == 1) ? K : V;
#pragma unroll
    for (int r = 0; r < 4; ++r) {
        int m = mtile * 16 + quad * 4 + r;
        float y = (acc[r] + bb) * sc;
        dst[(size_t)m * DIM + n] = (mat == 2) ? f2bf(y) : f2h(y);
    }
}

// ---------------- kernel 3: SPARSE attention, DPP reduce + pipelined gathers --
// Memory layout unchanged (coalesced row-pair gathers, 2 waves/row, full occ).
// Round-4 analysis: VALUBusy 45% (19us issue), dur 42us -> ~40% of cycles are
// stalls: (a) __shfl_xor -> ds_swizzle on the LDS pipe, serial in the
// per-neighbor chain; (b) gathers consumed immediately after issue (load-use
// distance 0 -> full L2 round-trip per iteration). This round:
//   * quad-reduce via DPP quad_perm (qsum4) — zero LDS-pipe ops in the loop
//   * software pipeline depth 1: iteration computes [n,n+4) while issuing
//     gathers for [n+4,n+8) and index-words for [n+8,n+12)
//   * launch_bounds(256,4): allocator headroom for the 2nd register set
//     (~60 VGPR expected -> still 7-8 waves/SIMD at runtime)
__global__ __launch_bounds__(256, 4) void sparse_attn(
    const u16* __restrict__ Q, const u16* __restrict__ K, const u16* __restrict__ V,
    const u16* __restrict__ NL, const u32* __restrict__ NC,
    u16* __restrict__ AO) {
    __shared__ float part[2][32][9];     // [row_in_block][t][O0..7, lsum] from wave half=1
    int tid  = threadIdx.x;
    int rb   = __builtin_amdgcn_readfirstlane(tid >> 7);         // row within block
    int half = __builtin_amdgcn_readfirstlane((tid >> 6) & 1);   // list half
    int lane = tid & 63;
    int p = lane >> 5;                   // neighbor parity within a pair
    int t = lane & 31;                   // 16B chunk index within the 512B row
    int row = __builtin_amdgcn_readfirstlane((int)blockIdx.x * 2 + rb);
    int pshift = p << 4;
    u32 tOff = (u32)(t * 8);             // element offset of this lane's chunk

    // Q slice (f16): 8 contiguous dims at t*8 (pre-scaled by 1/sqrt(HD)*log2e)
    uint4 qq = *(const uint4*)(Q + (size_t)row * DIM + t * 8);
    h2 qh0 = bch2(qq.x), qh1 = bch2(qq.y), qh2 = bch2(qq.z), qh3 = bch2(qq.w);

    f32x2 O0 = {0.f, 0.f}, O1 = {0.f, 0.f}, O2 = {0.f, 0.f}, O3 = {0.f, 0.f};
    float lsum = 0.f;

    int nnz = __builtin_amdgcn_readfirstlane((int)NC[row]);   // >= 1 (self-loop)
    const u16* lst = NL + (size_t)row * MAXNNZ;
    int nh    = ((nnz + 4) >> 3) << 2;   // split point, multiple of 4, ~nnz/2
    int begin = half ? nh : 0;
    int end   = half ? nnz : nh;

#define BODY(kk, vv, EVALID)                                                     \
    {                                                                            \
        float a = __builtin_amdgcn_fdot2(bch2(kk.x), qh0, 0.f, false);           \
        float b = __builtin_amdgcn_fdot2(bch2(kk.y), qh1, 0.f, false);           \
        a = __builtin_amdgcn_fdot2(bch2(kk.z), qh2, a, false);                   \
        b = __builtin_amdgcn_fdot2(bch2(kk.w), qh3, b, false);                   \
        float s = qsum4(a + b);          /* full 32-dim head dot, pure VALU */   \
        float e = __builtin_amdgcn_exp2f(s);                                     \
        if (!(EVALID)) e = 0.f;          /* folds away in the main loop */       \
        lsum += e;                                                               \
        f32x2 ev = {e, e};                                                       \
        O0 = __builtin_elementwise_fma(ev, (f32x2){blo(vv.x), bhi(vv.x)}, O0);   \
        O1 = __builtin_elementwise_fma(ev, (f32x2){blo(vv.y), bhi(vv.y)}, O1);   \
        O2 = __builtin_elementwise_fma(ev, (f32x2){blo(vv.z), bhi(vv.z)}, O2);   \
        O3 = __builtin_elementwise_fma(ev, (f32x2){blo(vv.w), bhi(vv.w)}, O3);   \
    }

    int n = begin;
    bool haveFull = (begin + 4 <= end);
    if (haveFull) {
        // prologue: issue gathers for [begin, begin+4) and index-words for the
        // following iteration. (All entries < end -> unclamped loads are safe.)
        u32 wA = *(const u32*)(lst + begin);
        u32 wB = *(const u32*)(lst + begin + 2);
        u32 offA = (((wA >> pshift) & 0xFFFFu) << 8) + tOff;
        u32 offB = (((wB >> pshift) & 0xFFFFu) << 8) + tOff;
        uint4 kA = *(const uint4*)(K + offA);
        uint4 vA = *(const uint4*)(V + offA);
        uint4 kB = *(const uint4*)(K + offB);
        uint4 vB = *(const uint4*)(V + offB);
        u32 wNA = *(const u32*)(lst + begin + 4);   // words for next iter
        u32 wNB = *(const u32*)(lst + begin + 6);   // (reads within NL row: safe)
        for (; n + 8 <= end; n += 4) {
            // issue next iteration's gathers (entries n+4..n+7 < end: valid)
            u32 offAn = (((wNA >> pshift) & 0xFFFFu) << 8) + tOff;
            u32 offBn = (((wNB >> pshift) & 0xFFFFu) << 8) + tOff;
            uint4 kAn = *(const uint4*)(K + offAn);
            uint4 vAn = *(const uint4*)(V + offAn);
            uint4 kBn = *(const uint4*)(K + offBn);
            uint4 vBn = *(const uint4*)(V + offBn);
            // words for the iteration after (value used only if loop continues;
            // read itself stays within the NL buffer + adjacent ws -> safe)
            wNA = *(const u32*)(lst + n + 8);
            wNB = *(const u32*)(lst + n + 10);
            // compute current iteration while the 4 next gathers are in flight
            BODY(kA, vA, true)
            BODY(kB, vB, true)
            kA = kAn; vA = vAn; kB = kBn; vB = vBn;
        }
        BODY(kA, vA, true)               // last full iteration (already in regs)
        BODY(kB, vB, true)
        n += 4;
    }
    if (n < end) {                       // ragged tail, 1..3 neighbors, masked
        u32 wA = *(const u32*)(lst + n);
        u32 wB = *(const u32*)(lst + n + 2);
        u32 lo = wA & 0xFFFFu;           // always a valid neighbor
        bool mA = (n + p) < end;
        bool mB = (n + 2 + p) < end;
        u32 idxA = mA ? ((wA >> pshift) & 0xFFFFu) : lo;
        u32 idxB = mB ? ((wB >> pshift) & 0xFFFFu) : lo;
        u32 offA = (idxA << 8) + tOff;
        u32 offB = (idxB << 8) + tOff;
        uint4 kT  = *(const uint4*)(K + offA);
        uint4 vT  = *(const uint4*)(V + offA);
        uint4 kT2 = *(const uint4*)(K + offB);
        uint4 vT2 = *(const uint4*)(V + offB);
        BODY(kT, vT, mA)
        BODY(kT2, vT2, mB)
    }
#undef BODY

    float Of[8] = {O0.x, O0.y, O1.x, O1.y, O2.x, O2.y, O3.x, O3.y};
    // combine the two parity halves (lanes differ in bit 5)
#pragma unroll
    for (int i = 0; i < 8; ++i) Of[i] += __shfl_xor(Of[i], 32, 64);
    lsum += __shfl_xor(lsum, 32, 64);

    // cross-wave combine through LDS (stride 9 floats: 9 coprime 32 -> no conflicts)
    if (half == 1 && p == 0) {
#pragma unroll
        for (int i = 0; i < 8; ++i) part[rb][t][i] = Of[i];
        part[rb][t][8] = lsum;
    }
    __syncthreads();
    if (half == 0 && p == 0) {
#pragma unroll
        for (int i = 0; i < 8; ++i) Of[i] += part[rb][t][i];
        lsum += part[rb][t][8];
        float inv = 1.0f / lsum;
        u32 w0 = (u32)f2bf(Of[0] * inv) | ((u32)f2bf(Of[1] * inv) << 16);
        u32 w1 = (u32)f2bf(Of[2] * inv) | ((u32)f2bf(Of[3] * inv) << 16);
        u32 w2 = (u32)f2bf(Of[4] * inv) | ((u32)f2bf(Of[5] * inv) << 16);
        u32 w3 = (u32)f2bf(Of[6] * inv) | ((u32)f2bf(Of[7] * inv) << 16);
        *(uint4*)(AO + (size_t)row * DIM + t * 8) = make_uint4(w0, w1, w2, w3);
    }
}

// ---------------- kernel 4: output projection (f32 out) ----------------
__global__ __launch_bounds__(64) void out_gemm(
    const u16* __restrict__ AO, const u16* __restrict__ WTo, const float* __restrict__ bo,
    float* __restrict__ out) {
    int lane = threadIdx.x, quad = lane >> 4, l16 = lane & 15;
    int mtile = blockIdx.x, ntile = blockIdx.y;
    const u16* arow = AO + (size_t)(mtile * 16 + l16) * DIM + quad * 8;
    const u16* brow = WTo + (size_t)(ntile * 16 + l16) * DIM + quad * 8;
    float4v acc = {0.f, 0.f, 0.f, 0.f};
#pragma unroll
    for (int k0 = 0; k0 < DIM; k0 += 32) {
        short8 af = *(const short8*)(arow + k0);
        short8 bf = *(const short8*)(brow + k0);
        acc = __builtin_amdgcn_mfma_f32_16x16x32_bf16(af, bf, acc, 0, 0, 0);
    }
    int n = ntile * 16 + l16;
    float bb = bo[n];
#pragma unroll
    for (int r = 0; r < 4; ++r)
        out[(size_t)(mtile * 16 + quad * 4 + r) * DIM + n] = acc[r] + bb;
}

extern "C" void kernel_launch(void* const* d_in, const int* in_sizes, int n_in,
                              void* d_out, int out_size, void* d_ws, size_t ws_size,
                              hipStream_t stream) {
    const float* x   = (const float*)d_in[0];
    const float* adj = (const float*)d_in[1];
    const float* Wq  = (const float*)d_in[2];
    const float* bq  = (const float*)d_in[3];
    const float* Wk  = (const float*)d_in[4];
    const float* bk  = (const float*)d_in[5];
    const float* Wv  = (const float*)d_in[6];
    const float* bv  = (const float*)d_in[7];
    const float* Wo  = (const float*)d_in[8];
    const float* bo  = (const float*)d_in[9];

    char* ws = (char*)d_ws;
    const size_t MB = 1u << 20;
    u16* Q   = (u16*)(ws);                          // 2 MB
    u16* K   = (u16*)(ws + 2 * MB);                 // 2 MB
    u16* V   = (u16*)(ws + 4 * MB);                 // 2 MB
    u16* AO  = (u16*)(ws + 6 * MB);                 // 2 MB
    u16* WT  = (u16*)(ws + 8 * MB);                 // 512 KB
    u16* XB  = (u16*)(ws + 8 * MB + 512 * 1024);    // 2 MB
    u16* NL  = (u16*)(ws + 11 * MB);                // 4 MB neighbor lists
    u32* NC  = (u32*)(ws + 15 * MB);                // 16 KB counts

    x_to_bf16<<<dim3(1024), 256, 0, stream>>>(x, XB);
    transpose_w<<<dim3(256, 4), 256, 0, stream>>>(Wq, Wk, Wv, Wo, WT);
    adj_to_list<<<dim3(4096), 256, 0, stream>>>(adj, NL, NC);
    qkv_gemm<<<dim3(256, 16, 3), 64, 0, stream>>>(XB, WT, bq, bk, bv, Q, K, V);
    sparse_attn<<<dim3(2048), 256, 0, stream>>>(Q, K, V, NL, NC, AO);
    out_gemm<<<dim3(256, 16), 64, 0, stream>>>(AO, WT + 3 * 65536, bo, (float*)d_out);
}

// Round 6
// 181.118 us; speedup vs baseline: 1.0614x; 1.0614x over previous
//
#include <hip/hip_runtime.h>
#include <hip/hip_bf16.h>
#include <stdint.h>

#define NTOK 4096
#define DIM  256
#define NH   8
#define HD   32
#define MAXNNZ 512   // per-row neighbor list capacity (mean ~205)

typedef __attribute__((ext_vector_type(8))) short short8;
typedef __attribute__((ext_vector_type(4))) float float4v;
typedef __attribute__((ext_vector_type(2))) float f32x2;
typedef __attribute__((ext_vector_type(2))) _Float16 h2;
typedef unsigned short u16;
typedef unsigned int u32;
typedef unsigned long long u64;

__device__ __forceinline__ float bf2f(u16 u) {
    union { u32 u; float f; } c; c.u = ((u32)u) << 16; return c.f;
}
__device__ __forceinline__ u16 f2bf(float f) {        // RNE
    union { float f; u32 u; } c; c.f = f;
    u32 u = c.u;
    u = u + 0x7FFFu + ((u >> 16) & 1u);
    return (u16)(u >> 16);
}
__device__ __forceinline__ u16 f2h(float f) {         // f32 -> f16 bits
    union { _Float16 h; u16 u; } c; c.h = (_Float16)f; return c.u;
}
__device__ __forceinline__ h2 bch2(u32 v) {           // u32 -> half2
    union { u32 u; h2 h; } c; c.u = v; return c.h;
}
// unpack a packed bf16 pair (u32) to two f32 without shifts on the hi half
__device__ __forceinline__ float blo(u32 c) {
    union { u32 u; float f; } x; x.u = c << 16; return x.f;
}
__device__ __forceinline__ float bhi(u32 c) {
    union { u32 u; float f; } x; x.u = c & 0xFFFF0000u; return x.f;
}
// sum across the 4-lane quad (lane bits 0-1) via DPP quad_perm — pure VALU.
__device__ __forceinline__ float qsum4(float s) {
    union { float f; int i; } c, r;
    c.f = s;
    r.i = __builtin_amdgcn_mov_dpp(c.i, 0xB1, 0xF, 0xF, true);  // [1,0,3,2]
    c.f += r.f;
    r.i = __builtin_amdgcn_mov_dpp(c.i, 0x4E, 0xF, 0xF, true);  // [2,3,0,1]
    return c.f + r.f;
}

// ---------------- kernel P: fused prep -------------------------------------
// blocks [0,4096)        : adjacency row -> neighbor list (ballot compaction)
// blocks [4096,5120)     : x f32 -> bf16 (4 floats/thread)
// blocks [5120,6144)     : weight transpose f32 -> bf16 WT
// Rationale: the three jobs are independent; fusing removes 2 launch gaps and
// lets the two small jobs run concurrently under adj's 67MB HBM read.
// Compaction: previous version did ~150 serialized LDS atomicAdds per block;
// now 4x __ballot + popc-prefix per pass, ONE atomic per wave per pass
// (16/block). List order is irrelevant (softmax sum is order-invariant).
__global__ __launch_bounds__(256) void prep(
    const float* __restrict__ x,
    const float* __restrict__ Wq, const float* __restrict__ Wk,
    const float* __restrict__ Wv, const float* __restrict__ Wo,
    const float* __restrict__ adj,
    u16* __restrict__ xb, u16* __restrict__ WT,
    u16* __restrict__ NL, u32* __restrict__ NC) {
    int b = blockIdx.x, t = threadIdx.x;
    if (b >= NTOK) {
        int m = b - NTOK;
        if (m < 1024) {                       // ---- x -> bf16 ----
            int i = (m * 256 + t) * 4;
            float4 v = *(const float4*)(x + i);
            ushort4 o;
            o.x = f2bf(v.x); o.y = f2bf(v.y); o.z = f2bf(v.z); o.w = f2bf(v.w);
            *(ushort4*)(xb + i) = o;
        } else {                              // ---- weight transpose ----
            m -= 1024;
            const float* srcs[4] = {Wq, Wk, Wv, Wo};
            int mat = m >> 8, o = m & 255;
            WT[mat * 65536 + o * 256 + t] = f2bf(srcs[mat][t * 256 + o]);
        }
        return;
    }
    // ---- adjacency row -> neighbor list ----
    __shared__ u32 cnt;
    if (t == 0) cnt = 0;
    __syncthreads();
    int lane = t & 63;
    u64 below = ((u64)1 << lane) - 1;
    const float4* rp = (const float4*)(adj + (size_t)b * NTOK);
    u16* lbase = NL + (size_t)b * MAXNNZ;
#pragma unroll
    for (int i = 0; i < 4; ++i) {
        float4 v = rp[i * 256 + t];
        bool px = v.x != 0.f, py = v.y != 0.f, pz = v.z != 0.f, pw = v.w != 0.f;
        u64 bx = __ballot(px), by = __ballot(py);
        u64 bz = __ballot(pz), bw = __ballot(pw);
        u32 cx = __popcll(bx), cy = __popcll(by), cz = __popcll(bz);
        u32 total = cx + cy + cz + __popcll(bw);
        u32 wbase = 0;
        if (lane == 0 && total) wbase = atomicAdd(&cnt, total);
        wbase = __shfl(wbase, 0, 64);
        int col0 = (i * 256 + t) * 4;
        u32 ox = wbase + __popcll(bx & below);
        u32 oy = wbase + cx + __popcll(by & below);
        u32 oz = wbase + cx + cy + __popcll(bz & below);
        u32 ow = wbase + cx + cy + cz + __popcll(bw & below);
        if (px && ox < MAXNNZ) lbase[ox] = (u16)(col0 + 0);
        if (py && oy < MAXNNZ) lbase[oy] = (u16)(col0 + 1);
        if (pz && oz < MAXNNZ) lbase[oz] = (u16)(col0 + 2);
        if (pw && ow < MAXNNZ) lbase[ow] = (u16)(col0 + 3);
    }
    __syncthreads();
    if (t == 0) NC[b] = (cnt < MAXNNZ) ? cnt : MAXNNZ;
}

// ---------------- kernel 2: QKV projection -----------------------------------
// Q, K written as f16 (feeds v_dot2_f32_f16 in sparse_attn); V stays bf16.
__global__ __launch_bounds__(64) void qkv_gemm(
    const u16* __restrict__ xb,
    const u16* __restrict__ WT,
    const float* __restrict__ bq, const float* __restrict__ bk, const float* __restrict__ bv,
    u16* __restrict__ Q, u16* __restrict__ K, u16* __restrict__ V) {
    int lane = threadIdx.x, quad = lane >> 4, l16 = lane & 15;
    int mtile = blockIdx.x, ntile = blockIdx.y, mat = blockIdx.z;
    const float* bias = (mat == 0) ? bq : (mat == 1) ? bk : bv;
    const u16* arow = xb + (size_t)(mtile * 16 + l16) * DIM + quad * 8;
    const u16* brow = WT + (size_t)mat * 65536 + (size_t)(ntile * 16 + l16) * DIM + quad * 8;
    float4v acc = {0.f, 0.f, 0.f, 0.f};
#pragma unroll
    for (int k0 = 0; k0 < DIM; k0 += 32) {
        short8 af = *(const short8*)(arow + k0);
        short8 bf = *(const short8*)(brow + k0);
        acc = __builtin_amdgcn_mfma_f32_16x16x32_bf16(af, bf, acc, 0, 0, 0);
    }
    int n = ntile * 16 + l16;
    float bb = bias[n];
    const float sc = (mat == 0) ? 0.25503635559913516f : 1.0f;  // 1/sqrt(32)*log2e
    u16* dst = (mat == 0) ? Q : (mat == 1) ? K : V;
#pragma unroll
    for (int r = 0; r < 4; ++r) {
        int m = mtile * 16 + quad * 4 + r;
        float y = (acc[r] + bb) * sc;
        dst[(size_t)m * DIM + n] = (mat == 2) ? f2bf(y) : f2h(y);
    }
}

// ---------------- kernel 3: SPARSE attention (unchanged from round 5) --------
__global__ __launch_bounds__(256, 4) void sparse_attn(
    const u16* __restrict__ Q, const u16* __restrict__ K, const u16* __restrict__ V,
    const u16* __restrict__ NL, const u32* __restrict__ NC,
    u16* __restrict__ AO) {
    __shared__ float part[2][32][9];     // [row_in_block][t][O0..7, lsum] from wave half=1
    int tid  = threadIdx.x;
    int rb   = __builtin_amdgcn_readfirstlane(tid >> 7);         // row within block
    int half = __builtin_amdgcn_readfirstlane((tid >> 6) & 1);   // list half
    int lane = tid & 63;
    int p = lane >> 5;                   // neighbor parity within a pair
    int t = lane & 31;                   // 16B chunk index within the 512B row
    int row = __builtin_amdgcn_readfirstlane((int)blockIdx.x * 2 + rb);
    int pshift = p << 4;
    u32 tOff = (u32)(t * 8);             // element offset of this lane's chunk

    // Q slice (f16): 8 contiguous dims at t*8 (pre-scaled by 1/sqrt(HD)*log2e)
    uint4 qq = *(const uint4*)(Q + (size_t)row * DIM + t * 8);
    h2 qh0 = bch2(qq.x), qh1 = bch2(qq.y), qh2 = bch2(qq.z), qh3 = bch2(qq.w);

    f32x2 O0 = {0.f, 0.f}, O1 = {0.f, 0.f}, O2 = {0.f, 0.f}, O3 = {0.f, 0.f};
    float lsum = 0.f;

    int nnz = __builtin_amdgcn_readfirstlane((int)NC[row]);   // >= 1 (self-loop)
    const u16* lst = NL + (size_t)row * MAXNNZ;
    int nh    = ((nnz + 4) >> 3) << 2;   // split point, multiple of 4, ~nnz/2
    int begin = half ? nh : 0;
    int end   = half ? nnz : nh;

#define BODY(kk, vv, EVALID)                                                     \
    {                                                                            \
        float a = __builtin_amdgcn_fdot2(bch2(kk.x), qh0, 0.f, false);           \
        float b = __builtin_amdgcn_fdot2(bch2(kk.y), qh1, 0.f, false);           \
        a = __builtin_amdgcn_fdot2(bch2(kk.z), qh2, a, false);                   \
        b = __builtin_amdgcn_fdot2(bch2(kk.w), qh3, b, false);                   \
        float s = qsum4(a + b);          /* full 32-dim head dot, pure VALU */   \
        float e = __builtin_amdgcn_exp2f(s);                                     \
        if (!(EVALID)) e = 0.f;          /* folds away in the main loop */       \
        lsum += e;                                                               \
        f32x2 ev = {e, e};                                                       \
        O0 = __builtin_elementwise_fma(ev, (f32x2){blo(vv.x), bhi(vv.x)}, O0);   \
        O1 = __builtin_elementwise_fma(ev, (f32x2){blo(vv.y), bhi(vv.y)}, O1);   \
        O2 = __builtin_elementwise_fma(ev, (f32x2){blo(vv.z), bhi(vv.z)}, O2);   \
        O3 = __builtin_elementwise_fma(ev, (f32x2){blo(vv.w), bhi(vv.w)}, O3);   \
    }

    int n = begin;
    bool haveFull = (begin + 4 <= end);
    if (haveFull) {
        u32 wA = *(const u32*)(lst + begin);
        u32 wB = *(const u32*)(lst + begin + 2);
        u32 offA = (((wA >> pshift) & 0xFFFFu) << 8) + tOff;
        u32 offB = (((wB >> pshift) & 0xFFFFu) << 8) + tOff;
        uint4 kA = *(const uint4*)(K + offA);
        uint4 vA = *(const uint4*)(V + offA);
        uint4 kB = *(const uint4*)(K + offB);
        uint4 vB = *(const uint4*)(V + offB);
        u32 wNA = *(const u32*)(lst + begin + 4);
        u32 wNB = *(const u32*)(lst + begin + 6);
        for (; n + 8 <= end; n += 4) {
            u32 offAn = (((wNA >> pshift) & 0xFFFFu) << 8) + tOff;
            u32 offBn = (((wNB >> pshift) & 0xFFFFu) << 8) + tOff;
            uint4 kAn = *(const uint4*)(K + offAn);
            uint4 vAn = *(const uint4*)(V + offAn);
            uint4 kBn = *(const uint4*)(K + offBn);
            uint4 vBn = *(const uint4*)(V + offBn);
            wNA = *(const u32*)(lst + n + 8);
            wNB = *(const u32*)(lst + n + 10);
            BODY(kA, vA, true)
            BODY(kB, vB, true)
            kA = kAn; vA = vAn; kB = kBn; vB = vBn;
        }
        BODY(kA, vA, true)
        BODY(kB, vB, true)
        n += 4;
    }
    if (n < end) {                       // ragged tail, 1..3 neighbors, masked
        u32 wA = *(const u32*)(lst + n);
        u32 wB = *(const u32*)(lst + n + 2);
        u32 lo = wA & 0xFFFFu;
        bool mA = (n + p) < end;
        bool mB = (n + 2 + p) < end;
        u32 idxA = mA ? ((wA >> pshift) & 0xFFFFu) : lo;
        u32 idxB = mB ? ((wB >> pshift) & 0xFFFFu) : lo;
        u32 offA = (idxA << 8) + tOff;
        u32 offB = (idxB << 8) + tOff;
        uint4 kT  = *(const uint4*)(K + offA);
        uint4 vT  = *(const uint4*)(V + offA);
        uint4 kT2 = *(const uint4*)(K + offB);
        uint4 vT2 = *(const uint4*)(V + offB);
        BODY(kT, vT, mA)
        BODY(kT2, vT2, mB)
    }
#undef BODY

    float Of[8] = {O0.x, O0.y, O1.x, O1.y, O2.x, O2.y, O3.x, O3.y};
#pragma unroll
    for (int i = 0; i < 8; ++i) Of[i] += __shfl_xor(Of[i], 32, 64);
    lsum += __shfl_xor(lsum, 32, 64);

    if (half == 1 && p == 0) {
#pragma unroll
        for (int i = 0; i < 8; ++i) part[rb][t][i] = Of[i];
        part[rb][t][8] = lsum;
    }
    __syncthreads();
    if (half == 0 && p == 0) {
#pragma unroll
        for (int i = 0; i < 8; ++i) Of[i] += part[rb][t][i];
        lsum += part[rb][t][8];
        float inv = 1.0f / lsum;
        u32 w0 = (u32)f2bf(Of[0] * inv) | ((u32)f2bf(Of[1] * inv) << 16);
        u32 w1 = (u32)f2bf(Of[2] * inv) | ((u32)f2bf(Of[3] * inv) << 16);
        u32 w2 = (u32)f2bf(Of[4] * inv) | ((u32)f2bf(Of[5] * inv) << 16);
        u32 w3 = (u32)f2bf(Of[6] * inv) | ((u32)f2bf(Of[7] * inv) << 16);
        *(uint4*)(AO + (size_t)row * DIM + t * 8) = make_uint4(w0, w1, w2, w3);
    }
}

// ---------------- kernel 4: output projection (f32 out) ----------------
__global__ __launch_bounds__(64) void out_gemm(
    const u16* __restrict__ AO, const u16* __restrict__ WTo, const float* __restrict__ bo,
    float* __restrict__ out) {
    int lane = threadIdx.x, quad = lane >> 4, l16 = lane & 15;
    int mtile = blockIdx.x, ntile = blockIdx.y;
    const u16* arow = AO + (size_t)(mtile * 16 + l16) * DIM + quad * 8;
    const u16* brow = WTo + (size_t)(ntile * 16 + l16) * DIM + quad * 8;
    float4v acc = {0.f, 0.f, 0.f, 0.f};
#pragma unroll
    for (int k0 = 0; k0 < DIM; k0 += 32) {
        short8 af = *(const short8*)(arow + k0);
        short8 bf = *(const short8*)(brow + k0);
        acc = __builtin_amdgcn_mfma_f32_16x16x32_bf16(af, bf, acc, 0, 0, 0);
    }
    int n = ntile * 16 + l16;
    float bb = bo[n];
#pragma unroll
    for (int r = 0; r < 4; ++r)
        out[(size_t)(mtile * 16 + quad * 4 + r) * DIM + n] = acc[r] + bb;
}

extern "C" void kernel_launch(void* const* d_in, const int* in_sizes, int n_in,
                              void* d_out, int out_size, void* d_ws, size_t ws_size,
                              hipStream_t stream) {
    const float* x   = (const float*)d_in[0];
    const float* adj = (const float*)d_in[1];
    const float* Wq  = (const float*)d_in[2];
    const float* bq  = (const float*)d_in[3];
    const float* Wk  = (const float*)d_in[4];
    const float* bk  = (const float*)d_in[5];
    const float* Wv  = (const float*)d_in[6];
    const float* bv  = (const float*)d_in[7];
    const float* Wo  = (const float*)d_in[8];
    const float* bo  = (const float*)d_in[9];

    char* ws = (char*)d_ws;
    const size_t MB = 1u << 20;
    u16* Q   = (u16*)(ws);                          // 2 MB
    u16* K   = (u16*)(ws + 2 * MB);                 // 2 MB
    u16* V   = (u16*)(ws + 4 * MB);                 // 2 MB
    u16* AO  = (u16*)(ws + 6 * MB);                 // 2 MB
    u16* WT  = (u16*)(ws + 8 * MB);                 // 512 KB
    u16* XB  = (u16*)(ws + 8 * MB + 512 * 1024);    // 2 MB
    u16* NL  = (u16*)(ws + 11 * MB);                // 4 MB neighbor lists
    u32* NC  = (u32*)(ws + 15 * MB);                // 16 KB counts

    prep<<<dim3(NTOK + 1024 + 1024), 256, 0, stream>>>(
        x, Wq, Wk, Wv, Wo, adj, XB, WT, NL, NC);
    qkv_gemm<<<dim3(256, 16, 3), 64, 0, stream>>>(XB, WT, bq, bk, bv, Q, K, V);
    sparse_attn<<<dim3(2048), 256, 0, stream>>>(Q, K, V, NL, NC, AO);
    out_gemm<<<dim3(256, 16), 64, 0, stream>>>(AO, WT + 3 * 65536, bo, (float*)d_out);
}